// Round 1
// baseline (798.300 us; speedup 1.0000x reference)
//
#include <hip/hip_runtime.h>

// Problem constants (match reference)
#define ED    32      // embedding / hidden dim
#define SEQ_T 200     // history length
#define NB    4096    // batch
#define H3    96      // 3*ED
#define PV_MAX 100000 // PV-1

__device__ __forceinline__ float rcp_fast(float x) { return __builtin_amdgcn_rcpf(x); }
__device__ __forceinline__ float sigmoid_fast(float x) { return rcp_fast(1.0f + __expf(-x)); }
__device__ __forceinline__ float tanh_fast(float x) {
  const float e = __expf(-2.0f * x);
  return (1.0f - e) * rcp_fast(1.0f + e);
}

// Broadcast lane K (0..31) within each 32-lane half-wave via ds_swizzle BitMode:
// offset = (xor<<10)|(or<<5)|and ; and=0, or=K -> every lane reads lane K of its group.
#define BCAST(v, K) \
  __uint_as_float((unsigned)__builtin_amdgcn_ds_swizzle((int)__float_as_uint(v), ((K) << 5)))

template <int TOWER>
__device__ __forceinline__ void fetch_idx(const int* __restrict__ ids,
                                          const float* __restrict__ prices,
                                          const int* __restrict__ depts,
                                          int base, int t, float pmean, float prsq,
                                          int& idx, bool& mk) {
  if constexpr (TOWER == 0) {
    idx = ids[base + t];
    mk = true;
  } else if constexpr (TOWER == 1) {
    const float p = prices[base + t];
    const float pn = (p - pmean) * prsq;
    mk = (pn != 0.0f);
    int q = (int)pn;                       // trunc toward zero, like astype(int32)
    q = q < 0 ? 0 : (q > PV_MAX ? PV_MAX : q);
    idx = q;
  } else {
    const int d = depts[base + t];
    mk = (d != 0);
    idx = d;
  }
}

template <int TOWER>
__device__ void tower_run(const int* __restrict__ ids,
                          const float* __restrict__ prices,
                          const int* __restrict__ depts,
                          const float* __restrict__ table,
                          const float* __restrict__ Wx,
                          const float* __restrict__ Wh,
                          const float* __restrict__ Bb,
                          float pmean, float prsq,
                          float* __restrict__ out) {
  const int j    = threadIdx.x & 31;                 // lane within row group = hidden index
  const int b    = blockIdx.x * 8 + (threadIdx.x >> 5);
  const int base = b * SEQ_T;

  // Loop-invariant weights -> registers (192 VGPRs). Lane j owns columns j, j+32, j+64.
  float wx0[ED], wx1[ED], wx2[ED], wh0[ED], wh1[ED], wh2[ED];
#pragma unroll
  for (int k = 0; k < ED; ++k) {
    wx0[k] = Wx[k * H3 + j];
    wx1[k] = Wx[k * H3 + 32 + j];
    wx2[k] = Wx[k * H3 + 64 + j];
    wh0[k] = Wh[k * H3 + j];
    wh1[k] = Wh[k * H3 + 32 + j];
    wh2[k] = Wh[k * H3 + 64 + j];
  }
  const float bi0 = Bb[j],      bi1 = Bb[32 + j],  bi2 = Bb[64 + j];
  const float bh0 = Bb[96 + j], bh1 = Bb[128 + j], bh2 = Bb[160 + j];

  float h = 0.0f;

  // Software-pipelined gather: prefetch x for step t+1 while computing step t.
  int idx0; bool mk_next;
  fetch_idx<TOWER>(ids, prices, depts, base, 0, pmean, prsq, idx0, mk_next);
  float x_next = table[(long)idx0 * ED + j];

  for (int t = 0; t < SEQ_T; ++t) {
    const float xv = x_next;
    const bool  mk = mk_next;
    if (t + 1 < SEQ_T) {
      int idn;
      fetch_idx<TOWER>(ids, prices, depts, base, t + 1, pmean, prsq, idn, mk_next);
      x_next = table[(long)idn * ED + j];
    }

    float a0 = bi0, a1 = bi1, a2 = bi2;   // x @ Wx + bi  (z, r, h chunks)
    float r0 = bh0, r1 = bh1, r2 = bh2;   // h @ Wh + bh

#define KSTEP(K)                              \
    {                                         \
      const float xk = BCAST(xv, K);          \
      const float hk = BCAST(h, K);           \
      a0 = __builtin_fmaf(xk, wx0[K], a0);    \
      a1 = __builtin_fmaf(xk, wx1[K], a1);    \
      a2 = __builtin_fmaf(xk, wx2[K], a2);    \
      r0 = __builtin_fmaf(hk, wh0[K], r0);    \
      r1 = __builtin_fmaf(hk, wh1[K], r1);    \
      r2 = __builtin_fmaf(hk, wh2[K], r2);    \
    }

    KSTEP(0)  KSTEP(1)  KSTEP(2)  KSTEP(3)
    KSTEP(4)  KSTEP(5)  KSTEP(6)  KSTEP(7)
    KSTEP(8)  KSTEP(9)  KSTEP(10) KSTEP(11)
    KSTEP(12) KSTEP(13) KSTEP(14) KSTEP(15)
    KSTEP(16) KSTEP(17) KSTEP(18) KSTEP(19)
    KSTEP(20) KSTEP(21) KSTEP(22) KSTEP(23)
    KSTEP(24) KSTEP(25) KSTEP(26) KSTEP(27)
    KSTEP(28) KSTEP(29) KSTEP(30) KSTEP(31)
#undef KSTEP

    const float z  = sigmoid_fast(a0 + r0);
    const float r  = sigmoid_fast(a1 + r1);
    const float hc = tanh_fast(a2 + r * r2);
    const float hn = z * h + (1.0f - z) * hc;
    h = mk ? hn : h;
  }

  out[b * H3 + TOWER * ED + j] = h;
}

__global__ __launch_bounds__(256, 2) void gru_towers(
    const int* __restrict__ ids, const float* __restrict__ prices, const int* __restrict__ depts,
    const float* __restrict__ item_table, const float* __restrict__ price_table,
    const float* __restrict__ dept_table,
    const float* __restrict__ item_Wx, const float* __restrict__ item_Wh,
    const float* __restrict__ item_b,
    const float* __restrict__ price_Wx, const float* __restrict__ price_Wh,
    const float* __restrict__ price_b,
    const float* __restrict__ dept_Wx, const float* __restrict__ dept_Wh,
    const float* __restrict__ dept_b,
    const float* __restrict__ price_mean, const float* __restrict__ price_var,
    float* __restrict__ out) {
  const int tower = blockIdx.y;
  if (tower == 0) {
    tower_run<0>(ids, prices, depts, item_table, item_Wx, item_Wh, item_b, 0.0f, 0.0f, out);
  } else if (tower == 1) {
    const float pm = price_mean[0];
    const float pr = rsqrtf(price_var[0]);
    tower_run<1>(ids, prices, depts, price_table, price_Wx, price_Wh, price_b, pm, pr, out);
  } else {
    tower_run<2>(ids, prices, depts, dept_table, dept_Wx, dept_Wh, dept_b, 0.0f, 0.0f, out);
  }
}

extern "C" void kernel_launch(void* const* d_in, const int* in_sizes, int n_in,
                              void* d_out, int out_size, void* d_ws, size_t ws_size,
                              hipStream_t stream) {
  const int*   ids         = (const int*)d_in[0];
  const float* prices      = (const float*)d_in[1];
  const int*   depts       = (const int*)d_in[2];
  const float* item_table  = (const float*)d_in[3];
  const float* price_table = (const float*)d_in[4];
  const float* dept_table  = (const float*)d_in[5];
  const float* item_Wx     = (const float*)d_in[6];
  const float* item_Wh     = (const float*)d_in[7];
  const float* item_b      = (const float*)d_in[8];
  const float* price_Wx    = (const float*)d_in[9];
  const float* price_Wh    = (const float*)d_in[10];
  const float* price_b     = (const float*)d_in[11];
  const float* dept_Wx     = (const float*)d_in[12];
  const float* dept_Wh     = (const float*)d_in[13];
  const float* dept_b      = (const float*)d_in[14];
  const float* price_mean  = (const float*)d_in[15];
  const float* price_var   = (const float*)d_in[16];
  float* out = (float*)d_out;

  dim3 grid(NB / 8, 3, 1);  // 512 row-blocks x 3 towers
  gru_towers<<<grid, 256, 0, stream>>>(
      ids, prices, depts, item_table, price_table, dept_table,
      item_Wx, item_Wh, item_b, price_Wx, price_Wh, price_b,
      dept_Wx, dept_Wh, dept_b, price_mean, price_var, out);
}

// Round 3
// 467.007 us; speedup vs baseline: 1.7094x; 1.7094x over previous
//
#include <hip/hip_runtime.h>

// Problem constants (match reference)
#define ED    32      // embedding / hidden dim
#define SEQ_T 200     // history length
#define NB    4096    // batch
#define H3    96      // 3*ED
#define IV    100001
#define PV    100001
#define DV    1001
#define PV_MAX 100000 // PV-1

// Pin a value into a VGPR: compiler cannot re-materialize the defining load
// inside the loop, because the asm "writes" the register.
#define PIN(x) asm volatile("" : "+v"(x))

__device__ __forceinline__ float rcp_fast(float x) { return __builtin_amdgcn_rcpf(x); }
__device__ __forceinline__ float sigmoid_fast(float x) { return rcp_fast(1.0f + __expf(-x)); }
__device__ __forceinline__ float tanh_fast(float x) {
  const float e = __expf(-2.0f * x);
  return (1.0f - e) * rcp_fast(1.0f + e);
}

// Broadcast lane K (0..31) within each 32-lane half-wave via ds_swizzle BitMode:
// offset = (xor<<10)|(or<<5)|and ; and=0, or=K -> every lane reads lane K of its group.
// K must be a literal constant (parse-time requirement of the builtin).
#define BCAST(v, K) \
  __uint_as_float((unsigned)__builtin_amdgcn_ds_swizzle((int)__float_as_uint(v), ((K) << 5)))

#define UNROLL32(M) \
  M(0)  M(1)  M(2)  M(3)  M(4)  M(5)  M(6)  M(7)  \
  M(8)  M(9)  M(10) M(11) M(12) M(13) M(14) M(15) \
  M(16) M(17) M(18) M(19) M(20) M(21) M(22) M(23) \
  M(24) M(25) M(26) M(27) M(28) M(29) M(30) M(31)

template <int TOWER>
__device__ __forceinline__ void fetch_idx(const int* __restrict__ ids,
                                          const float* __restrict__ prices,
                                          const int* __restrict__ depts,
                                          int base, int t, float pmean, float prsq,
                                          int& idx, bool& mk) {
  if constexpr (TOWER == 0) {
    idx = ids[base + t];
    mk = true;
  } else if constexpr (TOWER == 1) {
    const float p = prices[base + t];
    const float pn = (p - pmean) * prsq;
    mk = (pn != 0.0f);
    int q = (int)pn;                       // trunc toward zero, like astype(int32)
    q = q < 0 ? 0 : (q > PV_MAX ? PV_MAX : q);
    idx = q;
  } else {
    const int d = depts[base + t];
    mk = (d != 0);
    idx = d;
  }
}

// ---------------------------------------------------------------------------
// Phase 1: project embedding tables through Wx once: XP[v][c] = table[v] @ Wx.
// Layout: XP[v*96 + c], lane j covers c = j, j+32, j+64 (matches GRU reader).
// 256 threads = 8 row-groups, each group does 4 rows -> 32 rows/block.
// ---------------------------------------------------------------------------
__global__ __launch_bounds__(256, 2) void proj_table(
    const float* __restrict__ table, const float* __restrict__ Wx,
    float* __restrict__ XP, int nrows) {
  const int j  = threadIdx.x & 31;
  const int g  = threadIdx.x >> 5;
  const int r0 = blockIdx.x * 32 + g * 4;

  float wx0[ED], wx1[ED], wx2[ED];
#pragma unroll
  for (int k = 0; k < ED; ++k) {
    wx0[k] = Wx[k * H3 + j];
    wx1[k] = Wx[k * H3 + 32 + j];
    wx2[k] = Wx[k * H3 + 64 + j];
    PIN(wx0[k]); PIN(wx1[k]); PIN(wx2[k]);
  }

  for (int rr = 0; rr < 4; ++rr) {
    const int r = r0 + rr;
    if (r >= nrows) return;
    const float xv = table[(size_t)r * ED + j];
    float a0 = 0.f, a1 = 0.f, a2 = 0.f;
#define PSTEP(K)                              \
    {                                         \
      const float xk = BCAST(xv, K);          \
      a0 = __builtin_fmaf(xk, wx0[K], a0);    \
      a1 = __builtin_fmaf(xk, wx1[K], a1);    \
      a2 = __builtin_fmaf(xk, wx2[K], a2);    \
    }
    UNROLL32(PSTEP)
#undef PSTEP
    float* o = XP + (size_t)r * H3;
    o[j] = a0; o[32 + j] = a1; o[64 + j] = a2;
  }
}

// ---------------------------------------------------------------------------
// Phase 2: GRU recurrence with precomputed input projections.
// Per step: 3 coalesced xp loads + 32 h-broadcasts + 96 FMA + gates.
// ---------------------------------------------------------------------------
template <int TOWER>
__device__ void tower_pre(const int* __restrict__ ids,
                          const float* __restrict__ prices,
                          const int* __restrict__ depts,
                          const float* __restrict__ XP,
                          const float* __restrict__ Wh,
                          const float* __restrict__ Bb,
                          float pmean, float prsq,
                          float* __restrict__ out) {
  const int j    = threadIdx.x & 31;
  const int b    = blockIdx.x * 8 + (threadIdx.x >> 5);
  const int base = b * SEQ_T;

  float wh0[ED], wh1[ED], wh2[ED];
#pragma unroll
  for (int k = 0; k < ED; ++k) {
    wh0[k] = Wh[k * H3 + j];
    wh1[k] = Wh[k * H3 + 32 + j];
    wh2[k] = Wh[k * H3 + 64 + j];
    PIN(wh0[k]); PIN(wh1[k]); PIN(wh2[k]);
  }
  const float bi0 = Bb[j],      bi1 = Bb[32 + j],  bi2 = Bb[64 + j];
  const float bh0 = Bb[96 + j], bh1 = Bb[128 + j], bh2 = Bb[160 + j];

  float h = 0.0f;

  // Prefetch xp for step 0.
  int idx; bool mk_next;
  fetch_idx<TOWER>(ids, prices, depts, base, 0, pmean, prsq, idx, mk_next);
  const float* xr = XP + (size_t)idx * H3 + j;
  float x0 = xr[0], x1 = xr[32], x2 = xr[64];

  for (int t = 0; t < SEQ_T; ++t) {
    const float xv0 = x0, xv1 = x1, xv2 = x2;
    const bool  mk  = mk_next;
    if (t + 1 < SEQ_T) {
      int idn;
      fetch_idx<TOWER>(ids, prices, depts, base, t + 1, pmean, prsq, idn, mk_next);
      const float* xn = XP + (size_t)idn * H3 + j;
      x0 = xn[0]; x1 = xn[32]; x2 = xn[64];
    }

    float a0 = bi0 + xv0, a1 = bi1 + xv1, a2 = bi2 + xv2;  // x@Wx + bi (precomputed)
    float r0 = bh0, r1 = bh1, r2 = bh2;                    // h@Wh + bh

#define KSTEP(K)                              \
    {                                         \
      const float hk = BCAST(h, K);           \
      r0 = __builtin_fmaf(hk, wh0[K], r0);    \
      r1 = __builtin_fmaf(hk, wh1[K], r1);    \
      r2 = __builtin_fmaf(hk, wh2[K], r2);    \
    }
    UNROLL32(KSTEP)
#undef KSTEP

    const float z  = sigmoid_fast(a0 + r0);
    const float r  = sigmoid_fast(a1 + r1);
    const float hc = tanh_fast(a2 + r * r2);
    const float hn = z * h + (1.0f - z) * hc;
    h = mk ? hn : h;
  }

  out[b * H3 + TOWER * ED + j] = h;
}

__global__ __launch_bounds__(256, 2) void gru_pre(
    const int* __restrict__ ids, const float* __restrict__ prices, const int* __restrict__ depts,
    const float* __restrict__ itemXP, const float* __restrict__ priceXP,
    const float* __restrict__ deptXP,
    const float* __restrict__ item_Wh, const float* __restrict__ item_b,
    const float* __restrict__ price_Wh, const float* __restrict__ price_b,
    const float* __restrict__ dept_Wh, const float* __restrict__ dept_b,
    const float* __restrict__ price_mean, const float* __restrict__ price_var,
    float* __restrict__ out) {
  const int tower = blockIdx.y;
  if (tower == 0) {
    tower_pre<0>(ids, prices, depts, itemXP, item_Wh, item_b, 0.0f, 0.0f, out);
  } else if (tower == 1) {
    const float pm = price_mean[0];
    const float pr = rsqrtf(price_var[0]);
    tower_pre<1>(ids, prices, depts, priceXP, price_Wh, price_b, pm, pr, out);
  } else {
    tower_pre<2>(ids, prices, depts, deptXP, dept_Wh, dept_b, 0.0f, 0.0f, out);
  }
}

// ---------------------------------------------------------------------------
// Fallback (ws too small): fused in-loop x@Wx, with pinned weights.
// ---------------------------------------------------------------------------
template <int TOWER>
__device__ void tower_run(const int* __restrict__ ids,
                          const float* __restrict__ prices,
                          const int* __restrict__ depts,
                          const float* __restrict__ table,
                          const float* __restrict__ Wx,
                          const float* __restrict__ Wh,
                          const float* __restrict__ Bb,
                          float pmean, float prsq,
                          float* __restrict__ out) {
  const int j    = threadIdx.x & 31;
  const int b    = blockIdx.x * 8 + (threadIdx.x >> 5);
  const int base = b * SEQ_T;

  float wx0[ED], wx1[ED], wx2[ED], wh0[ED], wh1[ED], wh2[ED];
#pragma unroll
  for (int k = 0; k < ED; ++k) {
    wx0[k] = Wx[k * H3 + j];
    wx1[k] = Wx[k * H3 + 32 + j];
    wx2[k] = Wx[k * H3 + 64 + j];
    wh0[k] = Wh[k * H3 + j];
    wh1[k] = Wh[k * H3 + 32 + j];
    wh2[k] = Wh[k * H3 + 64 + j];
    PIN(wx0[k]); PIN(wx1[k]); PIN(wx2[k]);
    PIN(wh0[k]); PIN(wh1[k]); PIN(wh2[k]);
  }
  const float bi0 = Bb[j],      bi1 = Bb[32 + j],  bi2 = Bb[64 + j];
  const float bh0 = Bb[96 + j], bh1 = Bb[128 + j], bh2 = Bb[160 + j];

  float h = 0.0f;
  int idx; bool mk_next;
  fetch_idx<TOWER>(ids, prices, depts, base, 0, pmean, prsq, idx, mk_next);
  float x_next = table[(size_t)idx * ED + j];

  for (int t = 0; t < SEQ_T; ++t) {
    const float xv = x_next;
    const bool  mk = mk_next;
    if (t + 1 < SEQ_T) {
      int idn;
      fetch_idx<TOWER>(ids, prices, depts, base, t + 1, pmean, prsq, idn, mk_next);
      x_next = table[(size_t)idn * ED + j];
    }

    float a0 = bi0, a1 = bi1, a2 = bi2;
    float r0 = bh0, r1 = bh1, r2 = bh2;
#define KSTEP(K)                              \
    {                                         \
      const float xk = BCAST(xv, K);          \
      const float hk = BCAST(h, K);           \
      a0 = __builtin_fmaf(xk, wx0[K], a0);    \
      a1 = __builtin_fmaf(xk, wx1[K], a1);    \
      a2 = __builtin_fmaf(xk, wx2[K], a2);    \
      r0 = __builtin_fmaf(hk, wh0[K], r0);    \
      r1 = __builtin_fmaf(hk, wh1[K], r1);    \
      r2 = __builtin_fmaf(hk, wh2[K], r2);    \
    }
    UNROLL32(KSTEP)
#undef KSTEP

    const float z  = sigmoid_fast(a0 + r0);
    const float r  = sigmoid_fast(a1 + r1);
    const float hc = tanh_fast(a2 + r * r2);
    const float hn = z * h + (1.0f - z) * hc;
    h = mk ? hn : h;
  }
  out[b * H3 + TOWER * ED + j] = h;
}

__global__ __launch_bounds__(256, 2) void gru_towers(
    const int* __restrict__ ids, const float* __restrict__ prices, const int* __restrict__ depts,
    const float* __restrict__ item_table, const float* __restrict__ price_table,
    const float* __restrict__ dept_table,
    const float* __restrict__ item_Wx, const float* __restrict__ item_Wh,
    const float* __restrict__ item_b,
    const float* __restrict__ price_Wx, const float* __restrict__ price_Wh,
    const float* __restrict__ price_b,
    const float* __restrict__ dept_Wx, const float* __restrict__ dept_Wh,
    const float* __restrict__ dept_b,
    const float* __restrict__ price_mean, const float* __restrict__ price_var,
    float* __restrict__ out) {
  const int tower = blockIdx.y;
  if (tower == 0) {
    tower_run<0>(ids, prices, depts, item_table, item_Wx, item_Wh, item_b, 0.0f, 0.0f, out);
  } else if (tower == 1) {
    const float pm = price_mean[0];
    const float pr = rsqrtf(price_var[0]);
    tower_run<1>(ids, prices, depts, price_table, price_Wx, price_Wh, price_b, pm, pr, out);
  } else {
    tower_run<2>(ids, prices, depts, dept_table, dept_Wx, dept_Wh, dept_b, 0.0f, 0.0f, out);
  }
}

extern "C" void kernel_launch(void* const* d_in, const int* in_sizes, int n_in,
                              void* d_out, int out_size, void* d_ws, size_t ws_size,
                              hipStream_t stream) {
  const int*   ids         = (const int*)d_in[0];
  const float* prices      = (const float*)d_in[1];
  const int*   depts       = (const int*)d_in[2];
  const float* item_table  = (const float*)d_in[3];
  const float* price_table = (const float*)d_in[4];
  const float* dept_table  = (const float*)d_in[5];
  const float* item_Wx     = (const float*)d_in[6];
  const float* item_Wh     = (const float*)d_in[7];
  const float* item_b      = (const float*)d_in[8];
  const float* price_Wx    = (const float*)d_in[9];
  const float* price_Wh    = (const float*)d_in[10];
  const float* price_b     = (const float*)d_in[11];
  const float* dept_Wx     = (const float*)d_in[12];
  const float* dept_Wh     = (const float*)d_in[13];
  const float* dept_b      = (const float*)d_in[14];
  const float* price_mean  = (const float*)d_in[15];
  const float* price_var   = (const float*)d_in[16];
  float* out = (float*)d_out;

  const size_t need = (size_t)(IV + PV + DV) * H3 * sizeof(float);
  if (ws_size >= need) {
    float* itemXP  = (float*)d_ws;
    float* priceXP = itemXP + (size_t)IV * H3;
    float* deptXP  = priceXP + (size_t)PV * H3;

    proj_table<<<dim3((IV + 31) / 32), 256, 0, stream>>>(item_table,  item_Wx,  itemXP,  IV);
    proj_table<<<dim3((PV + 31) / 32), 256, 0, stream>>>(price_table, price_Wx, priceXP, PV);
    proj_table<<<dim3((DV + 31) / 32), 256, 0, stream>>>(dept_table,  dept_Wx,  deptXP,  DV);

    dim3 grid(NB / 8, 3, 1);
    gru_pre<<<grid, 256, 0, stream>>>(
        ids, prices, depts, itemXP, priceXP, deptXP,
        item_Wh, item_b, price_Wh, price_b, dept_Wh, dept_b,
        price_mean, price_var, out);
  } else {
    dim3 grid(NB / 8, 3, 1);
    gru_towers<<<grid, 256, 0, stream>>>(
        ids, prices, depts, item_table, price_table, dept_table,
        item_Wx, item_Wh, item_b, price_Wx, price_Wh, price_b,
        dept_Wx, dept_Wh, dept_b, price_mean, price_var, out);
  }
}